// Round 2
// baseline (237.712 us; speedup 1.0000x reference)
//
#include <hip/hip_runtime.h>
#include <cstdint>
#include <cstddef>

// GlobalAttention (Luong 'general'): q = src@W^T ; x = q@MB^T ; softmax(mask) ; c = P@MB
// Outputs: d_out = [ c (8*1024*256) | align_vectors (8*1024*4096) ] fp32.
// Pipeline: k_qproj -> k_logits (raw x + partial stats) -> k_stats -> k_pv (p + partial c) -> k_csum
//
// R1 fix: k_pv previously had 4 d-group waves each read raw x from global and
// write p back IN PLACE to the same addresses -> write/read race zeroed P blocks
// (absmax 4.28 ~ max|c|). Now each x element is converted to p by exactly ONE
// thread, p is shared to all waves via a swizzled LDS tile Ps, and the MFMA A
// fragments are read from LDS.

typedef _Float16 f16;
typedef _Float16 half8 __attribute__((ext_vector_type(8)));
typedef _Float16 half4v __attribute__((ext_vector_type(4)));
typedef float f32x4 __attribute__((ext_vector_type(4)));

#define MFMA16(a, b, c) __builtin_amdgcn_mfma_f32_16x16x32_f16((a), (b), (c), 0, 0, 0)

static constexpr int NBATCH = 8;
static constexpr int NT = 1024;   // TGT
static constexpr int NS = 4096;   // SRC
static constexpr int ND = 256;    // SDIM == TDIM
static constexpr float NEGBIG = -3.0e38f;

// XOR swizzle within a 128-byte LDS row (breaks 16-way bank conflicts on ds_read_b128)
__device__ __forceinline__ int swz(int row, int byteInRow) {
  return byteInRow ^ ((row & 7) << 4);
}

// ---------------- K1: q16 = source @ W^T (fp16 out) ----------------
// grid 128 (64 of 8192 flattened rows each), block 256 (4 waves: 2 t-groups x 2 n-groups)
__global__ __launch_bounds__(256) void k_qproj(const float* __restrict__ src,
                                               const float* __restrict__ W,
                                               f16* __restrict__ q16) {
  __shared__ __align__(16) f16 As[64 * 64];    // [t][k] swizzled rows of 128B
  __shared__ __align__(16) f16 Bs[256 * 64];   // [n][k] swizzled
  const int tid = threadIdx.x;
  const int w = tid >> 6, l = tid & 63;
  const int wt = w >> 1, wn = w & 1;
  const int q = l >> 4, lc = l & 15;
  const int t0 = blockIdx.x * 64;

  f32x4 acc[2][8];
#pragma unroll
  for (int i = 0; i < 2; ++i)
#pragma unroll
    for (int j = 0; j < 8; ++j) acc[i][j] = (f32x4){0.f, 0.f, 0.f, 0.f};

  for (int k0 = 0; k0 < 256; k0 += 64) {
    __syncthreads();
    {  // stage A: source tile 64x64 fp32 -> fp16 (thread: row tid/4, 2 chunks)
      const int r = tid >> 2, c2 = (tid & 3) * 2;
      const float* g = src + (size_t)(t0 + r) * 256 + k0 + c2 * 8;
      float4 f0 = ((const float4*)g)[0], f1 = ((const float4*)g)[1];
      float4 f2 = ((const float4*)g)[2], f3 = ((const float4*)g)[3];
      half8 h0 = {(f16)f0.x, (f16)f0.y, (f16)f0.z, (f16)f0.w,
                  (f16)f1.x, (f16)f1.y, (f16)f1.z, (f16)f1.w};
      half8 h1 = {(f16)f2.x, (f16)f2.y, (f16)f2.z, (f16)f2.w,
                  (f16)f3.x, (f16)f3.y, (f16)f3.z, (f16)f3.w};
      *(half8*)((char*)As + r * 128 + swz(r, c2 * 16)) = h0;
      *(half8*)((char*)As + r * 128 + swz(r, c2 * 16 + 16)) = h1;
    }
    {  // stage B: W tile 256x64 (W is [sdim][tdim] = [n][k] row-major: native)
      const int n = tid;
      const float* g = W + (size_t)n * 256 + k0;
#pragma unroll
      for (int c = 0; c < 8; ++c) {
        float4 f0 = ((const float4*)(g + c * 8))[0];
        float4 f1 = ((const float4*)(g + c * 8))[1];
        half8 h = {(f16)f0.x, (f16)f0.y, (f16)f0.z, (f16)f0.w,
                   (f16)f1.x, (f16)f1.y, (f16)f1.z, (f16)f1.w};
        *(half8*)((char*)Bs + n * 128 + swz(n, c * 16)) = h;
      }
    }
    __syncthreads();
    half8 a[2][2], bb[8][2];
#pragma unroll
    for (int mb = 0; mb < 2; ++mb)
#pragma unroll
      for (int kf = 0; kf < 2; ++kf) {
        const int r = wt * 32 + mb * 16 + lc;
        a[mb][kf] = *(const half8*)((const char*)As + r * 128 + swz(r, kf * 64 + q * 16));
      }
#pragma unroll
    for (int nb = 0; nb < 8; ++nb)
#pragma unroll
      for (int kf = 0; kf < 2; ++kf) {
        const int r = wn * 128 + nb * 16 + lc;
        bb[nb][kf] = *(const half8*)((const char*)Bs + r * 128 + swz(r, kf * 64 + q * 16));
      }
#pragma unroll
    for (int kf = 0; kf < 2; ++kf)
#pragma unroll
      for (int mb = 0; mb < 2; ++mb)
#pragma unroll
        for (int nb = 0; nb < 8; ++nb)
          acc[mb][nb] = MFMA16(a[mb][kf], bb[nb][kf], acc[mb][nb]);
  }
#pragma unroll
  for (int mb = 0; mb < 2; ++mb)
#pragma unroll
    for (int nb = 0; nb < 8; ++nb)
#pragma unroll
      for (int j = 0; j < 4; ++j) {
        const int t = t0 + wt * 32 + mb * 16 + q * 4 + j;  // C-layout: row=(l>>4)*4+j
        const int n = wn * 128 + nb * 16 + lc;             //           col=l&15
        q16[(size_t)t * 256 + n] = (f16)acc[mb][nb][j];
      }
}

// ---------------- K2: x = q16 @ MB^T, masked; raw x -> align region; partial stats ----
// grid (32 s-chunks, 4 t-tiles, 8 b), block 512 (8 waves: 4 t-groups x 2 s-groups)
// block tile 256t x 128s, K=256 in 4 steps of 64.
__global__ __launch_bounds__(512) void k_logits(const float* __restrict__ mbank,
                                                const f16* __restrict__ q16,
                                                const int* __restrict__ mask,
                                                float* __restrict__ alignv,
                                                float* __restrict__ pstats) {
  __shared__ __align__(16) f16 As[256 * 64];  // [t][k]
  __shared__ __align__(16) f16 Bs[128 * 64];  // [s][k]
  __shared__ float redm[2][256];
  __shared__ float reds[2][256];
  const int tid = threadIdx.x;
  const int w = tid >> 6, l = tid & 63;
  const int wt = w >> 1, wsg = w & 1;
  const int q = l >> 4, lc = l & 15;
  const int b = blockIdx.z;
  const int t0 = blockIdx.y * 256;
  const int s0 = blockIdx.x * 128;

  f32x4 acc[4][4];
#pragma unroll
  for (int i = 0; i < 4; ++i)
#pragma unroll
    for (int j = 0; j < 4; ++j) acc[i][j] = (f32x4){0.f, 0.f, 0.f, 0.f};

  for (int k0 = 0; k0 < 256; k0 += 64) {
    __syncthreads();
    {  // stage A from q16 (fp16, 256x64): thread: row tid/2, 4 chunks
      const int r = tid >> 1, c4 = (tid & 1) * 4;
      const half8* g = (const half8*)(q16 + (size_t)(b * NT + t0 + r) * 256 + k0 + c4 * 8);
#pragma unroll
      for (int c = 0; c < 4; ++c) {
        half8 h = g[c];
        *(half8*)((char*)As + r * 128 + swz(r, (c4 + c) * 16)) = h;
      }
    }
    {  // stage B from memory_bank fp32 (128x64): thread: row tid/4, 2 chunks
      const int s = tid >> 2, c2 = (tid & 3) * 2;
      const float* g = mbank + ((size_t)b * NS + s0 + s) * ND + k0 + c2 * 8;
      float4 f0 = ((const float4*)g)[0], f1 = ((const float4*)g)[1];
      float4 f2 = ((const float4*)g)[2], f3 = ((const float4*)g)[3];
      half8 h0 = {(f16)f0.x, (f16)f0.y, (f16)f0.z, (f16)f0.w,
                  (f16)f1.x, (f16)f1.y, (f16)f1.z, (f16)f1.w};
      half8 h1 = {(f16)f2.x, (f16)f2.y, (f16)f2.z, (f16)f2.w,
                  (f16)f3.x, (f16)f3.y, (f16)f3.z, (f16)f3.w};
      *(half8*)((char*)Bs + s * 128 + swz(s, c2 * 16)) = h0;
      *(half8*)((char*)Bs + s * 128 + swz(s, c2 * 16 + 16)) = h1;
    }
    __syncthreads();
    half8 a[4][2], bb[4][2];
#pragma unroll
    for (int mb = 0; mb < 4; ++mb)
#pragma unroll
      for (int kf = 0; kf < 2; ++kf) {
        const int r = wt * 64 + mb * 16 + lc;
        a[mb][kf] = *(const half8*)((const char*)As + r * 128 + swz(r, kf * 64 + q * 16));
      }
#pragma unroll
    for (int nb = 0; nb < 4; ++nb)
#pragma unroll
      for (int kf = 0; kf < 2; ++kf) {
        const int r = wsg * 64 + nb * 16 + lc;
        bb[nb][kf] = *(const half8*)((const char*)Bs + r * 128 + swz(r, kf * 64 + q * 16));
      }
#pragma unroll
    for (int kf = 0; kf < 2; ++kf)
#pragma unroll
      for (int mb = 0; mb < 4; ++mb)
#pragma unroll
        for (int nb = 0; nb < 4; ++nb)
          acc[mb][nb] = MFMA16(a[mb][kf], bb[nb][kf], acc[mb][nb]);
  }

  // epilogue: mask, store raw x, per-row partial max/sumexp over this 128-col chunk
  bool keep[4];
#pragma unroll
  for (int nb = 0; nb < 4; ++nb)
    keep[nb] = mask[(size_t)b * NS + s0 + wsg * 64 + nb * 16 + lc] != 0;

#pragma unroll
  for (int mb = 0; mb < 4; ++mb) {
#pragma unroll
    for (int j = 0; j < 4; ++j) {
      float v[4];
#pragma unroll
      for (int nb = 0; nb < 4; ++nb) v[nb] = keep[nb] ? acc[mb][nb][j] : NEGBIG;
      const int tl = wt * 64 + mb * 16 + q * 4 + j;
      float* ab = alignv + ((size_t)b * NT + t0 + tl) * NS + s0 + wsg * 64;
#pragma unroll
      for (int nb = 0; nb < 4; ++nb) ab[nb * 16 + lc] = v[nb];
      // reduce over this wave's 64 cols (lanes lc=0..15 hold 4 cols each)
      float m2 = fmaxf(fmaxf(v[0], v[1]), fmaxf(v[2], v[3]));
#pragma unroll
      for (int d = 1; d < 16; d <<= 1) m2 = fmaxf(m2, __shfl_xor(m2, d));
      float s2 = 0.f;
#pragma unroll
      for (int nb = 0; nb < 4; ++nb) s2 += __expf(v[nb] - m2);
#pragma unroll
      for (int d = 1; d < 16; d <<= 1) s2 += __shfl_xor(s2, d);
      if (lc == 0) { redm[wsg][tl] = m2; reds[wsg][tl] = s2; }
    }
  }
  __syncthreads();
  if (tid < 256) {  // merge two s-wave-groups -> one partial per (row, 128-chunk)
    const float m0 = redm[0][tid], m1 = redm[1][tid];
    const float mm = fmaxf(m0, m1);
    const float ss = reds[0][tid] * __expf(m0 - mm) + reds[1][tid] * __expf(m1 - mm);
    const size_t rg = (size_t)b * NT + t0 + tid;
    pstats[(rg * 32 + blockIdx.x) * 2 + 0] = mm;
    pstats[(rg * 32 + blockIdx.x) * 2 + 1] = ss;
  }
}

// ---------------- K3: reduce 32 chunk partials -> m, 1/l per row ----------------
__global__ __launch_bounds__(256) void k_stats(const float* __restrict__ pstats,
                                               float* __restrict__ sm,
                                               float* __restrict__ slinv) {
  const int r = blockIdx.x * 256 + threadIdx.x;  // 0..8191
  const float4* p = (const float4*)(pstats + (size_t)r * 64);
  float4 v[16];
  float mm = NEGBIG;
#pragma unroll
  for (int i = 0; i < 16; ++i) {
    v[i] = p[i];
    mm = fmaxf(mm, fmaxf(v[i].x, v[i].z));
  }
  float ll = 0.f;
#pragma unroll
  for (int i = 0; i < 16; ++i)
    ll += v[i].y * __expf(v[i].x - mm) + v[i].w * __expf(v[i].z - mm);
  sm[r] = mm;
  slinv[r] = (ll > 0.f) ? (1.f / ll) : 0.f;
}

// ---------------- K4: p = exp(x-m)/l (once per element, in place) ; partial c = P@V ----
// grid (4 s-chunks, 8 t-tiles, 8 b), block 512 (8 waves: 2 t-groups x 4 d-groups)
// block tile 128t x 256d, src-chunk 1024 in 16 steps of 64.
// Each thread owns a disjoint (t, 16-s) slab of the 128x64 p-tile: sole
// reader/writer of those x elements; p is broadcast to all waves via LDS Ps.
__global__ __launch_bounds__(512) void k_pv(const float* __restrict__ mbank,
                                            const float* __restrict__ sm,
                                            const float* __restrict__ slinv,
                                            float* __restrict__ alignv,
                                            float* __restrict__ pc) {
  __shared__ __align__(16) f16 VT[256 * 64];  // [d][s] transposed, swizzled
  __shared__ __align__(16) f16 Ps[128 * 64];  // [t][s] p-tile fp16, swizzled
  const int tid = threadIdx.x;
  const int w = tid >> 6, l = tid & 63;
  const int wt = w >> 2, wd = w & 3;  // wt in {0,1}, wd in {0..3}
  const int q = l >> 4, lc = l & 15;
  const int kc = blockIdx.x;
  const int t0 = blockIdx.y * 128;
  const int b = blockIdx.z;
  const int s0 = kc * 1024;

  // p-conversion ownership: thread -> row pt (0..127), s-slab ps (16 wide)
  const int pt = tid >> 2;
  const int ps = (tid & 3) * 16;
  const float mv = sm[(size_t)b * NT + t0 + pt];
  const float lv = slinv[(size_t)b * NT + t0 + pt];

  f32x4 acc[4][4];
#pragma unroll
  for (int i = 0; i < 4; ++i)
#pragma unroll
    for (int j = 0; j < 4; ++j) acc[i][j] = (f32x4){0.f, 0.f, 0.f, 0.f};

  const int dstage = (w & 3) * 64 + l;  // this thread's V^T row (shared across waves 0-3/4-7)
  const int shalf = (w >> 2) * 32;      // which 32-s half this wave stages

  for (int st = 0; st < 16; ++st) {
    const int sb = s0 + st * 64;
    __syncthreads();  // protect VT/Ps reuse from previous iteration's reads
    {                 // stage V^T: lane holds 4 consecutive s at fixed d -> packed b64 write
#pragma unroll
      for (int i = 0; i < 8; ++i) {
        const int s4 = shalf + i * 4;
        const float* g = mbank + ((size_t)b * NS + sb + s4) * ND + dstage;
        const float f0 = g[0], f1 = g[ND], f2 = g[2 * ND], f3 = g[3 * ND];
        half4v h = {(f16)f0, (f16)f1, (f16)f2, (f16)f3};
        *(half4v*)((char*)VT + dstage * 128 + swz(dstage, s4 * 2)) = h;
      }
    }
    {  // x -> p, exactly once per element; write p to global + fp16 to LDS
      float* xp = alignv + ((size_t)b * NT + t0 + pt) * NS + sb + ps;
      float4 x0 = ((const float4*)xp)[0];
      float4 x1 = ((const float4*)xp)[1];
      float4 x2 = ((const float4*)xp)[2];
      float4 x3 = ((const float4*)xp)[3];
      const float p0 = __expf(x0.x - mv) * lv, p1 = __expf(x0.y - mv) * lv;
      const float p2 = __expf(x0.z - mv) * lv, p3 = __expf(x0.w - mv) * lv;
      const float p4 = __expf(x1.x - mv) * lv, p5 = __expf(x1.y - mv) * lv;
      const float p6 = __expf(x1.z - mv) * lv, p7 = __expf(x1.w - mv) * lv;
      const float p8 = __expf(x2.x - mv) * lv, p9 = __expf(x2.y - mv) * lv;
      const float pa = __expf(x2.z - mv) * lv, pb = __expf(x2.w - mv) * lv;
      const float pcv = __expf(x3.x - mv) * lv, pd = __expf(x3.y - mv) * lv;
      const float pe = __expf(x3.z - mv) * lv, pf = __expf(x3.w - mv) * lv;
      ((float4*)xp)[0] = (float4){p0, p1, p2, p3};
      ((float4*)xp)[1] = (float4){p4, p5, p6, p7};
      ((float4*)xp)[2] = (float4){p8, p9, pa, pb};
      ((float4*)xp)[3] = (float4){pcv, pd, pe, pf};
      half8 h0 = {(f16)p0, (f16)p1, (f16)p2, (f16)p3,
                  (f16)p4, (f16)p5, (f16)p6, (f16)p7};
      half8 h1 = {(f16)p8, (f16)p9, (f16)pa, (f16)pb,
                  (f16)pcv, (f16)pd, (f16)pe, (f16)pf};
      *(half8*)((char*)Ps + pt * 128 + swz(pt, ps * 2)) = h0;
      *(half8*)((char*)Ps + pt * 128 + swz(pt, ps * 2 + 16)) = h1;
    }
    __syncthreads();
    half8 a[4][2];
#pragma unroll
    for (int mb = 0; mb < 4; ++mb)
#pragma unroll
      for (int kf = 0; kf < 2; ++kf) {
        const int r = wt * 64 + mb * 16 + lc;
        a[mb][kf] = *(const half8*)((const char*)Ps + r * 128 + swz(r, kf * 64 + q * 16));
      }
    half8 bb[4][2];
#pragma unroll
    for (int nb = 0; nb < 4; ++nb)
#pragma unroll
      for (int kf = 0; kf < 2; ++kf) {
        const int d = wd * 64 + nb * 16 + lc;
        bb[nb][kf] = *(const half8*)((const char*)VT + d * 128 + swz(d, kf * 64 + q * 16));
      }
#pragma unroll
    for (int kf = 0; kf < 2; ++kf)
#pragma unroll
      for (int mb = 0; mb < 4; ++mb)
#pragma unroll
        for (int nb = 0; nb < 4; ++nb)
          acc[mb][nb] = MFMA16(a[mb][kf], bb[nb][kf], acc[mb][nb]);
  }

#pragma unroll
  for (int mb = 0; mb < 4; ++mb)
#pragma unroll
    for (int nb = 0; nb < 4; ++nb)
#pragma unroll
      for (int j = 0; j < 4; ++j) {
        const int t = t0 + wt * 64 + mb * 16 + q * 4 + j;
        const int d = wd * 64 + nb * 16 + lc;
        pc[(size_t)kc * ((size_t)NBATCH * NT * ND) + ((size_t)b * NT + t) * ND + d] =
            acc[mb][nb][j];
      }
}

// ---------------- K5: c = sum of 4 split-K partials ----------------
__global__ __launch_bounds__(256) void k_csum(const float* __restrict__ pc,
                                              float* __restrict__ outc) {
  const size_t i4 = ((size_t)blockIdx.x * 256 + threadIdx.x) * 4;
  const size_t STRIDE = (size_t)NBATCH * NT * ND;  // 2097152
  float4 a = *(const float4*)(pc + i4);
  float4 b = *(const float4*)(pc + STRIDE + i4);
  float4 c = *(const float4*)(pc + 2 * STRIDE + i4);
  float4 d = *(const float4*)(pc + 3 * STRIDE + i4);
  float4 r;
  r.x = a.x + b.x + c.x + d.x;
  r.y = a.y + b.y + c.y + d.y;
  r.z = a.z + b.z + c.z + d.z;
  r.w = a.w + b.w + c.w + d.w;
  *(float4*)(outc + i4) = r;
}

extern "C" void kernel_launch(void* const* d_in, const int* in_sizes, int n_in,
                              void* d_out, int out_size, void* d_ws, size_t ws_size,
                              hipStream_t stream) {
  const float* mbank = (const float*)d_in[0];  // (8,4096,256) f32
  const float* src   = (const float*)d_in[1];  // (8,1024,256) f32
  const int*   mask  = (const int*)d_in[2];    // (8,4096) bool->int
  const float* W     = (const float*)d_in[3];  // (256,256) f32

  float* out_c = (float*)d_out;                         // 2,097,152 f32
  float* out_align = out_c + (size_t)NBATCH * NT * ND;  // 33,554,432 f32

  // ws layout (pc overlays q16+pstats, which are dead by the time K4 writes pc):
  //   [0, 33554432)           pc   : 4 x 8M f32 split-K partials     (K4 -> K5)
  //   [0, 4194304)            q16  : 8192x256 fp16                    (K1 -> K2)
  //   [4194304, 6291456)      pstats: 8192x32x2 f32                   (K2 -> K3)
  //   [33554432, 33587200)    sm   : 8192 f32
  //   [33587200, 33619968)    slinv: 8192 f32
  char* ws = (char*)d_ws;
  f16* q16      = (f16*)ws;
  float* pstats = (float*)(ws + 4194304);
  float* pc     = (float*)ws;
  float* sm     = (float*)(ws + 33554432);
  float* slinv  = (float*)(ws + 33587200);

  hipLaunchKernelGGL(k_qproj, dim3(128), dim3(256), 0, stream, src, W, q16);
  hipLaunchKernelGGL(k_logits, dim3(32, 4, 8), dim3(512), 0, stream,
                     mbank, q16, mask, out_align, pstats);
  hipLaunchKernelGGL(k_stats, dim3(32), dim3(256), 0, stream, pstats, sm, slinv);
  hipLaunchKernelGGL(k_pv, dim3(4, 8, 8), dim3(512), 0, stream,
                     mbank, sm, slinv, out_align, pc);
  hipLaunchKernelGGL(k_csum, dim3(2048), dim3(256), 0, stream, pc, out_c);
}

// Round 3
// 155.056 us; speedup vs baseline: 1.5331x; 1.5331x over previous
//
#include <hip/hip_runtime.h>
#include <cstdint>
#include <cstddef>

// GlobalAttention (Luong 'general'): q = src@W^T ; x = q@MB^T ; softmax(mask) ; c = P@MB
// Outputs: d_out = [ c (8*1024*256) | align_vectors (8*1024*4096) ] fp32.
// Pipeline: k_qproj -> k_logits (raw x + partial stats) -> k_stats -> k_pv (p + partial c) -> k_csum
//
// R2: k_pv was latency-bound (occ 16%, MfmaUtil 4%, 2.4 TB/s): 256 blocks = 1/CU,
// 8 barrier-locked waves, no overlap. Now: t-tile 64 -> 512 blocks (2/CU, 16
// waves/CU, launch_bounds(512,4) caps VGPR<=128), plus T14 async-stage: next
// step's x prefetched into regs and consumed at the next write phase, hidden
// under ds_read+MFMA+barriers.

typedef _Float16 f16;
typedef _Float16 half8 __attribute__((ext_vector_type(8)));
typedef _Float16 half4v __attribute__((ext_vector_type(4)));
typedef float f32x4 __attribute__((ext_vector_type(4)));

#define MFMA16(a, b, c) __builtin_amdgcn_mfma_f32_16x16x32_f16((a), (b), (c), 0, 0, 0)

static constexpr int NBATCH = 8;
static constexpr int NT = 1024;   // TGT
static constexpr int NS = 4096;   // SRC
static constexpr int ND = 256;    // SDIM == TDIM
static constexpr float NEGBIG = -3.0e38f;

// XOR swizzle within a 128-byte LDS row (breaks 16-way bank conflicts on ds_read_b128)
__device__ __forceinline__ int swz(int row, int byteInRow) {
  return byteInRow ^ ((row & 7) << 4);
}

// ---------------- K1: q16 = source @ W^T (fp16 out) ----------------
// grid 128 (64 of 8192 flattened rows each), block 256 (4 waves: 2 t-groups x 2 n-groups)
__global__ __launch_bounds__(256) void k_qproj(const float* __restrict__ src,
                                               const float* __restrict__ W,
                                               f16* __restrict__ q16) {
  __shared__ __align__(16) f16 As[64 * 64];    // [t][k] swizzled rows of 128B
  __shared__ __align__(16) f16 Bs[256 * 64];   // [n][k] swizzled
  const int tid = threadIdx.x;
  const int w = tid >> 6, l = tid & 63;
  const int wt = w >> 1, wn = w & 1;
  const int q = l >> 4, lc = l & 15;
  const int t0 = blockIdx.x * 64;

  f32x4 acc[2][8];
#pragma unroll
  for (int i = 0; i < 2; ++i)
#pragma unroll
    for (int j = 0; j < 8; ++j) acc[i][j] = (f32x4){0.f, 0.f, 0.f, 0.f};

  for (int k0 = 0; k0 < 256; k0 += 64) {
    __syncthreads();
    {  // stage A: source tile 64x64 fp32 -> fp16 (thread: row tid/4, 2 chunks)
      const int r = tid >> 2, c2 = (tid & 3) * 2;
      const float* g = src + (size_t)(t0 + r) * 256 + k0 + c2 * 8;
      float4 f0 = ((const float4*)g)[0], f1 = ((const float4*)g)[1];
      float4 f2 = ((const float4*)g)[2], f3 = ((const float4*)g)[3];
      half8 h0 = {(f16)f0.x, (f16)f0.y, (f16)f0.z, (f16)f0.w,
                  (f16)f1.x, (f16)f1.y, (f16)f1.z, (f16)f1.w};
      half8 h1 = {(f16)f2.x, (f16)f2.y, (f16)f2.z, (f16)f2.w,
                  (f16)f3.x, (f16)f3.y, (f16)f3.z, (f16)f3.w};
      *(half8*)((char*)As + r * 128 + swz(r, c2 * 16)) = h0;
      *(half8*)((char*)As + r * 128 + swz(r, c2 * 16 + 16)) = h1;
    }
    {  // stage B: W tile 256x64 (W is [sdim][tdim] = [n][k] row-major: native)
      const int n = tid;
      const float* g = W + (size_t)n * 256 + k0;
#pragma unroll
      for (int c = 0; c < 8; ++c) {
        float4 f0 = ((const float4*)(g + c * 8))[0];
        float4 f1 = ((const float4*)(g + c * 8))[1];
        half8 h = {(f16)f0.x, (f16)f0.y, (f16)f0.z, (f16)f0.w,
                   (f16)f1.x, (f16)f1.y, (f16)f1.z, (f16)f1.w};
        *(half8*)((char*)Bs + n * 128 + swz(n, c * 16)) = h;
      }
    }
    __syncthreads();
    half8 a[2][2], bb[8][2];
#pragma unroll
    for (int mb = 0; mb < 2; ++mb)
#pragma unroll
      for (int kf = 0; kf < 2; ++kf) {
        const int r = wt * 32 + mb * 16 + lc;
        a[mb][kf] = *(const half8*)((const char*)As + r * 128 + swz(r, kf * 64 + q * 16));
      }
#pragma unroll
    for (int nb = 0; nb < 8; ++nb)
#pragma unroll
      for (int kf = 0; kf < 2; ++kf) {
        const int r = wn * 128 + nb * 16 + lc;
        bb[nb][kf] = *(const half8*)((const char*)Bs + r * 128 + swz(r, kf * 64 + q * 16));
      }
#pragma unroll
    for (int kf = 0; kf < 2; ++kf)
#pragma unroll
      for (int mb = 0; mb < 2; ++mb)
#pragma unroll
        for (int nb = 0; nb < 8; ++nb)
          acc[mb][nb] = MFMA16(a[mb][kf], bb[nb][kf], acc[mb][nb]);
  }
#pragma unroll
  for (int mb = 0; mb < 2; ++mb)
#pragma unroll
    for (int nb = 0; nb < 8; ++nb)
#pragma unroll
      for (int j = 0; j < 4; ++j) {
        const int t = t0 + wt * 32 + mb * 16 + q * 4 + j;  // C-layout: row=(l>>4)*4+j
        const int n = wn * 128 + nb * 16 + lc;             //           col=l&15
        q16[(size_t)t * 256 + n] = (f16)acc[mb][nb][j];
      }
}

// ---------------- K2: x = q16 @ MB^T, masked; raw x -> align region; partial stats ----
// grid (32 s-chunks, 4 t-tiles, 8 b), block 512 (8 waves: 4 t-groups x 2 s-groups)
// block tile 256t x 128s, K=256 in 4 steps of 64.
__global__ __launch_bounds__(512) void k_logits(const float* __restrict__ mbank,
                                                const f16* __restrict__ q16,
                                                const int* __restrict__ mask,
                                                float* __restrict__ alignv,
                                                float* __restrict__ pstats) {
  __shared__ __align__(16) f16 As[256 * 64];  // [t][k]
  __shared__ __align__(16) f16 Bs[128 * 64];  // [s][k]
  __shared__ float redm[2][256];
  __shared__ float reds[2][256];
  const int tid = threadIdx.x;
  const int w = tid >> 6, l = tid & 63;
  const int wt = w >> 1, wsg = w & 1;
  const int q = l >> 4, lc = l & 15;
  const int b = blockIdx.z;
  const int t0 = blockIdx.y * 256;
  const int s0 = blockIdx.x * 128;

  f32x4 acc[4][4];
#pragma unroll
  for (int i = 0; i < 4; ++i)
#pragma unroll
    for (int j = 0; j < 4; ++j) acc[i][j] = (f32x4){0.f, 0.f, 0.f, 0.f};

  for (int k0 = 0; k0 < 256; k0 += 64) {
    __syncthreads();
    {  // stage A from q16 (fp16, 256x64): thread: row tid/2, 4 chunks
      const int r = tid >> 1, c4 = (tid & 1) * 4;
      const half8* g = (const half8*)(q16 + (size_t)(b * NT + t0 + r) * 256 + k0 + c4 * 8);
#pragma unroll
      for (int c = 0; c < 4; ++c) {
        half8 h = g[c];
        *(half8*)((char*)As + r * 128 + swz(r, (c4 + c) * 16)) = h;
      }
    }
    {  // stage B from memory_bank fp32 (128x64): thread: row tid/4, 2 chunks
      const int s = tid >> 2, c2 = (tid & 3) * 2;
      const float* g = mbank + ((size_t)b * NS + s0 + s) * ND + k0 + c2 * 8;
      float4 f0 = ((const float4*)g)[0], f1 = ((const float4*)g)[1];
      float4 f2 = ((const float4*)g)[2], f3 = ((const float4*)g)[3];
      half8 h0 = {(f16)f0.x, (f16)f0.y, (f16)f0.z, (f16)f0.w,
                  (f16)f1.x, (f16)f1.y, (f16)f1.z, (f16)f1.w};
      half8 h1 = {(f16)f2.x, (f16)f2.y, (f16)f2.z, (f16)f2.w,
                  (f16)f3.x, (f16)f3.y, (f16)f3.z, (f16)f3.w};
      *(half8*)((char*)Bs + s * 128 + swz(s, c2 * 16)) = h0;
      *(half8*)((char*)Bs + s * 128 + swz(s, c2 * 16 + 16)) = h1;
    }
    __syncthreads();
    half8 a[4][2], bb[4][2];
#pragma unroll
    for (int mb = 0; mb < 4; ++mb)
#pragma unroll
      for (int kf = 0; kf < 2; ++kf) {
        const int r = wt * 64 + mb * 16 + lc;
        a[mb][kf] = *(const half8*)((const char*)As + r * 128 + swz(r, kf * 64 + q * 16));
      }
#pragma unroll
    for (int nb = 0; nb < 4; ++nb)
#pragma unroll
      for (int kf = 0; kf < 2; ++kf) {
        const int r = wsg * 64 + nb * 16 + lc;
        bb[nb][kf] = *(const half8*)((const char*)Bs + r * 128 + swz(r, kf * 64 + q * 16));
      }
#pragma unroll
    for (int kf = 0; kf < 2; ++kf)
#pragma unroll
      for (int mb = 0; mb < 4; ++mb)
#pragma unroll
        for (int nb = 0; nb < 4; ++nb)
          acc[mb][nb] = MFMA16(a[mb][kf], bb[nb][kf], acc[mb][nb]);
  }

  // epilogue: mask, store raw x, per-row partial max/sumexp over this 128-col chunk
  bool keep[4];
#pragma unroll
  for (int nb = 0; nb < 4; ++nb)
    keep[nb] = mask[(size_t)b * NS + s0 + wsg * 64 + nb * 16 + lc] != 0;

#pragma unroll
  for (int mb = 0; mb < 4; ++mb) {
#pragma unroll
    for (int j = 0; j < 4; ++j) {
      float v[4];
#pragma unroll
      for (int nb = 0; nb < 4; ++nb) v[nb] = keep[nb] ? acc[mb][nb][j] : NEGBIG;
      const int tl = wt * 64 + mb * 16 + q * 4 + j;
      float* ab = alignv + ((size_t)b * NT + t0 + tl) * NS + s0 + wsg * 64;
#pragma unroll
      for (int nb = 0; nb < 4; ++nb) ab[nb * 16 + lc] = v[nb];
      // reduce over this wave's 64 cols (lanes lc=0..15 hold 4 cols each)
      float m2 = fmaxf(fmaxf(v[0], v[1]), fmaxf(v[2], v[3]));
#pragma unroll
      for (int d = 1; d < 16; d <<= 1) m2 = fmaxf(m2, __shfl_xor(m2, d));
      float s2 = 0.f;
#pragma unroll
      for (int nb = 0; nb < 4; ++nb) s2 += __expf(v[nb] - m2);
#pragma unroll
      for (int d = 1; d < 16; d <<= 1) s2 += __shfl_xor(s2, d);
      if (lc == 0) { redm[wsg][tl] = m2; reds[wsg][tl] = s2; }
    }
  }
  __syncthreads();
  if (tid < 256) {  // merge two s-wave-groups -> one partial per (row, 128-chunk)
    const float m0 = redm[0][tid], m1 = redm[1][tid];
    const float mm = fmaxf(m0, m1);
    const float ss = reds[0][tid] * __expf(m0 - mm) + reds[1][tid] * __expf(m1 - mm);
    const size_t rg = (size_t)b * NT + t0 + tid;
    pstats[(rg * 32 + blockIdx.x) * 2 + 0] = mm;
    pstats[(rg * 32 + blockIdx.x) * 2 + 1] = ss;
  }
}

// ---------------- K3: reduce 32 chunk partials -> m, 1/l per row ----------------
__global__ __launch_bounds__(256) void k_stats(const float* __restrict__ pstats,
                                               float* __restrict__ sm,
                                               float* __restrict__ slinv) {
  const int r = blockIdx.x * 256 + threadIdx.x;  // 0..8191
  const float4* p = (const float4*)(pstats + (size_t)r * 64);
  float4 v[16];
  float mm = NEGBIG;
#pragma unroll
  for (int i = 0; i < 16; ++i) {
    v[i] = p[i];
    mm = fmaxf(mm, fmaxf(v[i].x, v[i].z));
  }
  float ll = 0.f;
#pragma unroll
  for (int i = 0; i < 16; ++i)
    ll += v[i].y * __expf(v[i].x - mm) + v[i].w * __expf(v[i].z - mm);
  sm[r] = mm;
  slinv[r] = (ll > 0.f) ? (1.f / ll) : 0.f;
}

// ---------------- K4: p = exp(x-m)/l (once per element, in place) ; partial c = P@V ----
// grid (4 s-chunks, 16 t-tiles, 8 b) = 512 blocks, block 512 (8 waves: 2 t x 4 d)
// block tile 64t x 256d, src-chunk 1024 in 16 steps of 64.
// T14: x for step st+1 prefetched into regs after step st's p-conversion
// consumed the old values; loads fly during ds_read+MFMA+barriers.
__global__ __launch_bounds__(512, 4) void k_pv(const float* __restrict__ mbank,
                                               const float* __restrict__ sm,
                                               const float* __restrict__ slinv,
                                               float* __restrict__ alignv,
                                               float* __restrict__ pc) {
  __shared__ __align__(16) f16 VT[256 * 64];  // [d][s] transposed, swizzled (32 KB)
  __shared__ __align__(16) f16 Ps[64 * 64];   // [t][s] p-tile fp16, swizzled (8 KB)
  const int tid = threadIdx.x;
  const int w = tid >> 6, l = tid & 63;
  const int wtg = w >> 2, wd = w & 3;  // wtg in {0,1} (32 rows), wd in {0..3} (64 d)
  const int q = l >> 4, lc = l & 15;
  const int kc = blockIdx.x;
  const int t0 = blockIdx.y * 64;
  const int b = blockIdx.z;
  const int s0 = kc * 1024;

  // p-conversion ownership: thread -> row pt (0..63), 8-wide s-slab ps8
  const int pt = tid >> 3;
  const int ps8 = (tid & 7) * 8;
  const float mv = sm[(size_t)b * NT + t0 + pt];
  const float lv = slinv[(size_t)b * NT + t0 + pt];
  float* xrow = alignv + ((size_t)b * NT + t0 + pt) * NS + s0 + ps8;

  f32x4 acc[2][4];
#pragma unroll
  for (int i = 0; i < 2; ++i)
#pragma unroll
    for (int j = 0; j < 4; ++j) acc[i][j] = (f32x4){0.f, 0.f, 0.f, 0.f};

  const int dstage = wd * 64 + l;   // this thread's V^T row (waves 0-3 / 4-7 alias)
  const int shalf = wtg * 32;       // which 32-s half this wave stages

  // prefetch x for step 0
  float4 xA = ((const float4*)xrow)[0];
  float4 xB = ((const float4*)xrow)[1];

  for (int st = 0; st < 16; ++st) {
    const int sb = s0 + st * 64;
    __syncthreads();  // prev step's MFMA done reading VT/Ps
    {  // stage V^T: 4 consecutive s at fixed d -> packed b64 write (32 elem/thread)
#pragma unroll
      for (int i = 0; i < 8; ++i) {
        const int s4 = shalf + i * 4;
        const float* g = mbank + ((size_t)b * NS + sb + s4) * ND + dstage;
        const float f0 = g[0], f1 = g[ND], f2 = g[2 * ND], f3 = g[3 * ND];
        half4v h = {(f16)f0, (f16)f1, (f16)f2, (f16)f3};
        *(half4v*)((char*)VT + dstage * 128 + swz(dstage, s4 * 2)) = h;
      }
    }
    {  // x -> p from prefetched regs; write p to global + fp16 to LDS
      const float p0 = __expf(xA.x - mv) * lv, p1 = __expf(xA.y - mv) * lv;
      const float p2 = __expf(xA.z - mv) * lv, p3 = __expf(xA.w - mv) * lv;
      const float p4 = __expf(xB.x - mv) * lv, p5 = __expf(xB.y - mv) * lv;
      const float p6 = __expf(xB.z - mv) * lv, p7 = __expf(xB.w - mv) * lv;
      float* xp = xrow + st * 64;
      ((float4*)xp)[0] = (float4){p0, p1, p2, p3};
      ((float4*)xp)[1] = (float4){p4, p5, p6, p7};
      half8 h = {(f16)p0, (f16)p1, (f16)p2, (f16)p3,
                 (f16)p4, (f16)p5, (f16)p6, (f16)p7};
      *(half8*)((char*)Ps + pt * 128 + swz(pt, ps8 * 2)) = h;
    }
    if (st < 15) {  // T14: issue next step's x loads (consumed next iteration)
      const float* xn = xrow + (st + 1) * 64;
      xA = ((const float4*)xn)[0];
      xB = ((const float4*)xn)[1];
    }
    __syncthreads();  // VT/Ps ready
    half8 a[2][2];
#pragma unroll
    for (int mb = 0; mb < 2; ++mb)
#pragma unroll
      for (int kf = 0; kf < 2; ++kf) {
        const int r = wtg * 32 + mb * 16 + lc;
        a[mb][kf] = *(const half8*)((const char*)Ps + r * 128 + swz(r, kf * 64 + q * 16));
      }
#pragma unroll
    for (int kf = 0; kf < 2; ++kf)
#pragma unroll
      for (int nb = 0; nb < 4; ++nb) {
        const int d = wd * 64 + nb * 16 + lc;
        half8 bbt = *(const half8*)((const char*)VT + d * 128 + swz(d, kf * 64 + q * 16));
#pragma unroll
        for (int mb = 0; mb < 2; ++mb)
          acc[mb][nb] = MFMA16(a[mb][kf], bbt, acc[mb][nb]);
      }
  }

#pragma unroll
  for (int mb = 0; mb < 2; ++mb)
#pragma unroll
    for (int nb = 0; nb < 4; ++nb)
#pragma unroll
      for (int j = 0; j < 4; ++j) {
        const int t = t0 + wtg * 32 + mb * 16 + q * 4 + j;
        const int d = wd * 64 + nb * 16 + lc;
        pc[(size_t)kc * ((size_t)NBATCH * NT * ND) + ((size_t)b * NT + t) * ND + d] =
            acc[mb][nb][j];
      }
}

// ---------------- K5: c = sum of 4 split-K partials ----------------
__global__ __launch_bounds__(256) void k_csum(const float* __restrict__ pc,
                                              float* __restrict__ outc) {
  const size_t i4 = ((size_t)blockIdx.x * 256 + threadIdx.x) * 4;
  const size_t STRIDE = (size_t)NBATCH * NT * ND;  // 2097152
  float4 a = *(const float4*)(pc + i4);
  float4 b = *(const float4*)(pc + STRIDE + i4);
  float4 c = *(const float4*)(pc + 2 * STRIDE + i4);
  float4 d = *(const float4*)(pc + 3 * STRIDE + i4);
  float4 r;
  r.x = a.x + b.x + c.x + d.x;
  r.y = a.y + b.y + c.y + d.y;
  r.z = a.z + b.z + c.z + d.z;
  r.w = a.w + b.w + c.w + d.w;
  *(float4*)(outc + i4) = r;
}

extern "C" void kernel_launch(void* const* d_in, const int* in_sizes, int n_in,
                              void* d_out, int out_size, void* d_ws, size_t ws_size,
                              hipStream_t stream) {
  const float* mbank = (const float*)d_in[0];  // (8,4096,256) f32
  const float* src   = (const float*)d_in[1];  // (8,1024,256) f32
  const int*   mask  = (const int*)d_in[2];    // (8,4096) bool->int
  const float* W     = (const float*)d_in[3];  // (256,256) f32

  float* out_c = (float*)d_out;                         // 2,097,152 f32
  float* out_align = out_c + (size_t)NBATCH * NT * ND;  // 33,554,432 f32

  // ws layout (pc overlays q16+pstats, which are dead by the time K4 writes pc):
  //   [0, 33554432)           pc   : 4 x 8M f32 split-K partials     (K4 -> K5)
  //   [0, 4194304)            q16  : 8192x256 fp16                    (K1 -> K2)
  //   [4194304, 6291456)      pstats: 8192x32x2 f32                   (K2 -> K3)
  //   [33554432, 33587200)    sm   : 8192 f32
  //   [33587200, 33619968)    slinv: 8192 f32
  char* ws = (char*)d_ws;
  f16* q16      = (f16*)ws;
  float* pstats = (float*)(ws + 4194304);
  float* pc     = (float*)ws;
  float* sm     = (float*)(ws + 33554432);
  float* slinv  = (float*)(ws + 33587200);

  hipLaunchKernelGGL(k_qproj, dim3(128), dim3(256), 0, stream, src, W, q16);
  hipLaunchKernelGGL(k_logits, dim3(32, 4, 8), dim3(512), 0, stream,
                     mbank, q16, mask, out_align, pstats);
  hipLaunchKernelGGL(k_stats, dim3(32), dim3(256), 0, stream, pstats, sm, slinv);
  hipLaunchKernelGGL(k_pv, dim3(4, 16, 8), dim3(512), 0, stream,
                     mbank, sm, slinv, out_align, pc);
  hipLaunchKernelGGL(k_csum, dim3(2048), dim3(256), 0, stream, pc, out_c);
}

// Round 4
// 146.266 us; speedup vs baseline: 1.6252x; 1.0601x over previous
//
#include <hip/hip_runtime.h>
#include <cstdint>
#include <cstddef>

// GlobalAttention (Luong 'general'): q = src@W^T ; x = q@MB^T ; softmax(mask) ; c = P@MB
// Outputs: d_out = [ c (8*1024*256) | align_vectors (8*1024*4096) ] fp32.
// Pipeline: k_qproj -> k_logits (raw x + partial stats) -> k_stats -> k_pv (p + partial c) -> k_csum
//
// R3: k_logits was latency-bound (occ 20.8%, 2.19 TB/s): 52KB LDS -> <=3 blocks/CU,
// 8 barrier-locked waves. Now 128t x 64s tiles, 256-thread blocks (4 waves, each
// wave owns 32t x 64s -> no cross-wave reduce), 24KB LDS, grid 4096, T14 reg
// prefetch of next K-step. Split-K pc partials now fp16 (halves k_csum traffic).

typedef _Float16 f16;
typedef _Float16 half8 __attribute__((ext_vector_type(8)));
typedef _Float16 half4v __attribute__((ext_vector_type(4)));
typedef float f32x4 __attribute__((ext_vector_type(4)));

#define MFMA16(a, b, c) __builtin_amdgcn_mfma_f32_16x16x32_f16((a), (b), (c), 0, 0, 0)

static constexpr int NBATCH = 8;
static constexpr int NT = 1024;   // TGT
static constexpr int NS = 4096;   // SRC
static constexpr int ND = 256;    // SDIM == TDIM
static constexpr float NEGBIG = -3.0e38f;

// XOR swizzle within a 128-byte LDS row (breaks 16-way bank conflicts on ds_read_b128)
__device__ __forceinline__ int swz(int row, int byteInRow) {
  return byteInRow ^ ((row & 7) << 4);
}

// ---------------- K1: q16 = source @ W^T (fp16 out) ----------------
// grid 128 (64 of 8192 flattened rows each), block 256 (4 waves: 2 t-groups x 2 n-groups)
__global__ __launch_bounds__(256) void k_qproj(const float* __restrict__ src,
                                               const float* __restrict__ W,
                                               f16* __restrict__ q16) {
  __shared__ __align__(16) f16 As[64 * 64];    // [t][k] swizzled rows of 128B
  __shared__ __align__(16) f16 Bs[256 * 64];   // [n][k] swizzled
  const int tid = threadIdx.x;
  const int w = tid >> 6, l = tid & 63;
  const int wt = w >> 1, wn = w & 1;
  const int q = l >> 4, lc = l & 15;
  const int t0 = blockIdx.x * 64;

  f32x4 acc[2][8];
#pragma unroll
  for (int i = 0; i < 2; ++i)
#pragma unroll
    for (int j = 0; j < 8; ++j) acc[i][j] = (f32x4){0.f, 0.f, 0.f, 0.f};

  for (int k0 = 0; k0 < 256; k0 += 64) {
    __syncthreads();
    {  // stage A: source tile 64x64 fp32 -> fp16 (thread: row tid/4, 2 chunks)
      const int r = tid >> 2, c2 = (tid & 3) * 2;
      const float* g = src + (size_t)(t0 + r) * 256 + k0 + c2 * 8;
      float4 f0 = ((const float4*)g)[0], f1 = ((const float4*)g)[1];
      float4 f2 = ((const float4*)g)[2], f3 = ((const float4*)g)[3];
      half8 h0 = {(f16)f0.x, (f16)f0.y, (f16)f0.z, (f16)f0.w,
                  (f16)f1.x, (f16)f1.y, (f16)f1.z, (f16)f1.w};
      half8 h1 = {(f16)f2.x, (f16)f2.y, (f16)f2.z, (f16)f2.w,
                  (f16)f3.x, (f16)f3.y, (f16)f3.z, (f16)f3.w};
      *(half8*)((char*)As + r * 128 + swz(r, c2 * 16)) = h0;
      *(half8*)((char*)As + r * 128 + swz(r, c2 * 16 + 16)) = h1;
    }
    {  // stage B: W tile 256x64 (W is [sdim][tdim] = [n][k] row-major: native)
      const int n = tid;
      const float* g = W + (size_t)n * 256 + k0;
#pragma unroll
      for (int c = 0; c < 8; ++c) {
        float4 f0 = ((const float4*)(g + c * 8))[0];
        float4 f1 = ((const float4*)(g + c * 8))[1];
        half8 h = {(f16)f0.x, (f16)f0.y, (f16)f0.z, (f16)f0.w,
                   (f16)f1.x, (f16)f1.y, (f16)f1.z, (f16)f1.w};
        *(half8*)((char*)Bs + n * 128 + swz(n, c * 16)) = h;
      }
    }
    __syncthreads();
    half8 a[2][2], bb[8][2];
#pragma unroll
    for (int mb = 0; mb < 2; ++mb)
#pragma unroll
      for (int kf = 0; kf < 2; ++kf) {
        const int r = wt * 32 + mb * 16 + lc;
        a[mb][kf] = *(const half8*)((const char*)As + r * 128 + swz(r, kf * 64 + q * 16));
      }
#pragma unroll
    for (int nb = 0; nb < 8; ++nb)
#pragma unroll
      for (int kf = 0; kf < 2; ++kf) {
        const int r = wn * 128 + nb * 16 + lc;
        bb[nb][kf] = *(const half8*)((const char*)Bs + r * 128 + swz(r, kf * 64 + q * 16));
      }
#pragma unroll
    for (int kf = 0; kf < 2; ++kf)
#pragma unroll
      for (int mb = 0; mb < 2; ++mb)
#pragma unroll
        for (int nb = 0; nb < 8; ++nb)
          acc[mb][nb] = MFMA16(a[mb][kf], bb[nb][kf], acc[mb][nb]);
  }
#pragma unroll
  for (int mb = 0; mb < 2; ++mb)
#pragma unroll
    for (int nb = 0; nb < 8; ++nb)
#pragma unroll
      for (int j = 0; j < 4; ++j) {
        const int t = t0 + wt * 32 + mb * 16 + q * 4 + j;  // C-layout: row=(l>>4)*4+j
        const int n = wn * 128 + nb * 16 + lc;             //           col=l&15
        q16[(size_t)t * 256 + n] = (f16)acc[mb][nb][j];
      }
}

// ---------------- K2: x = q16 @ MB^T, masked; raw x -> align region; partial stats ----
// grid (64 s-chunks, 8 t-tiles, 8 b) = 4096 blocks, block 256 (4 waves, each 32t x 64s)
// block tile 128t x 64s, K=256 in 4 steps of 64. T14 reg prefetch of next K-step.
__global__ __launch_bounds__(256, 4) void k_logits(const float* __restrict__ mbank,
                                                   const f16* __restrict__ q16,
                                                   const int* __restrict__ mask,
                                                   float* __restrict__ alignv,
                                                   float* __restrict__ pstats) {
  __shared__ __align__(16) f16 As[128 * 64];  // [t][k] 16 KB
  __shared__ __align__(16) f16 Bs[64 * 64];   // [s][k] 8 KB
  const int tid = threadIdx.x;
  const int w = tid >> 6, l = tid & 63;
  const int q = l >> 4, lc = l & 15;
  const int b = blockIdx.z;
  const int t0 = blockIdx.y * 128;
  const int s0 = blockIdx.x * 64;

  // staging ownership
  const int ar = tid >> 1, ac = (tid & 1) * 32;          // A: row, f16-col base (4x half8)
  const int br = tid >> 2, bc = (tid & 3) * 16;          // B: row, f32-col base (4x float4)
  const f16* gA = q16 + (size_t)(b * NT + t0 + ar) * 256 + ac;
  const float* gB = mbank + ((size_t)b * NS + s0 + br) * ND + bc;

  f32x4 acc[2][4];
#pragma unroll
  for (int i = 0; i < 2; ++i)
#pragma unroll
    for (int j = 0; j < 4; ++j) acc[i][j] = (f32x4){0.f, 0.f, 0.f, 0.f};

  // prologue: prefetch K-step 0
  half8 pa0, pa1, pa2, pa3;
  float4 pb0, pb1, pb2, pb3;
  pa0 = ((const half8*)gA)[0]; pa1 = ((const half8*)gA)[1];
  pa2 = ((const half8*)gA)[2]; pa3 = ((const half8*)gA)[3];
  pb0 = ((const float4*)gB)[0]; pb1 = ((const float4*)gB)[1];
  pb2 = ((const float4*)gB)[2]; pb3 = ((const float4*)gB)[3];

  for (int ks = 0; ks < 4; ++ks) {
    __syncthreads();  // prev MFMA done reading LDS
    {  // regs -> LDS
      char* pA = (char*)As + ar * 128;
      *(half8*)(pA + swz(ar, ac * 2)) = pa0;
      *(half8*)(pA + swz(ar, ac * 2 + 16)) = pa1;
      *(half8*)(pA + swz(ar, ac * 2 + 32)) = pa2;
      *(half8*)(pA + swz(ar, ac * 2 + 48)) = pa3;
      half8 h0 = {(f16)pb0.x, (f16)pb0.y, (f16)pb0.z, (f16)pb0.w,
                  (f16)pb1.x, (f16)pb1.y, (f16)pb1.z, (f16)pb1.w};
      half8 h1 = {(f16)pb2.x, (f16)pb2.y, (f16)pb2.z, (f16)pb2.w,
                  (f16)pb3.x, (f16)pb3.y, (f16)pb3.z, (f16)pb3.w};
      char* pB = (char*)Bs + br * 128;
      *(half8*)(pB + swz(br, bc * 2)) = h0;
      *(half8*)(pB + swz(br, bc * 2 + 16)) = h1;
    }
    if (ks < 3) {  // T14: issue next K-step loads; land during MFMA phase
      const f16* nA = gA + (ks + 1) * 64;
      const float* nB = gB + (ks + 1) * 64;
      pa0 = ((const half8*)nA)[0]; pa1 = ((const half8*)nA)[1];
      pa2 = ((const half8*)nA)[2]; pa3 = ((const half8*)nA)[3];
      pb0 = ((const float4*)nB)[0]; pb1 = ((const float4*)nB)[1];
      pb2 = ((const float4*)nB)[2]; pb3 = ((const float4*)nB)[3];
    }
    __syncthreads();  // LDS ready
    half8 a[2][2];
#pragma unroll
    for (int mb = 0; mb < 2; ++mb)
#pragma unroll
      for (int kf = 0; kf < 2; ++kf) {
        const int r = w * 32 + mb * 16 + lc;
        a[mb][kf] = *(const half8*)((const char*)As + r * 128 + swz(r, kf * 64 + q * 16));
      }
#pragma unroll
    for (int kf = 0; kf < 2; ++kf)
#pragma unroll
      for (int nb = 0; nb < 4; ++nb) {
        const int s = nb * 16 + lc;
        half8 bbt = *(const half8*)((const char*)Bs + s * 128 + swz(s, kf * 64 + q * 16));
#pragma unroll
        for (int mb = 0; mb < 2; ++mb)
          acc[mb][nb] = MFMA16(a[mb][kf], bbt, acc[mb][nb]);
      }
  }

  // epilogue: mask, store raw x, per-row partial max/sumexp over this 64-col chunk.
  // Each row's 64 cols live in one 16-lane q-group (4 frags x 16 lanes).
  bool keep[4];
#pragma unroll
  for (int nb = 0; nb < 4; ++nb)
    keep[nb] = mask[(size_t)b * NS + s0 + nb * 16 + lc] != 0;

#pragma unroll
  for (int mb = 0; mb < 2; ++mb) {
#pragma unroll
    for (int j = 0; j < 4; ++j) {
      float v[4];
#pragma unroll
      for (int nb = 0; nb < 4; ++nb) v[nb] = keep[nb] ? acc[mb][nb][j] : NEGBIG;
      const int tl = w * 32 + mb * 16 + q * 4 + j;
      float* ab = alignv + ((size_t)b * NT + t0 + tl) * NS + s0;
#pragma unroll
      for (int nb = 0; nb < 4; ++nb) ab[nb * 16 + lc] = v[nb];
      float m2 = fmaxf(fmaxf(v[0], v[1]), fmaxf(v[2], v[3]));
#pragma unroll
      for (int d = 1; d < 16; d <<= 1) m2 = fmaxf(m2, __shfl_xor(m2, d));
      float s2 = 0.f;
#pragma unroll
      for (int nb = 0; nb < 4; ++nb) s2 += __expf(v[nb] - m2);
#pragma unroll
      for (int d = 1; d < 16; d <<= 1) s2 += __shfl_xor(s2, d);
      if (lc == 0) {
        const size_t rg = (size_t)b * NT + t0 + tl;
        pstats[(rg * 64 + blockIdx.x) * 2 + 0] = m2;
        pstats[(rg * 64 + blockIdx.x) * 2 + 1] = s2;
      }
    }
  }
}

// ---------------- K3: reduce 64 chunk partials -> m, 1/l per row ----------------
__global__ __launch_bounds__(256) void k_stats(const float* __restrict__ pstats,
                                               float* __restrict__ sm,
                                               float* __restrict__ slinv) {
  const int r = blockIdx.x * 256 + threadIdx.x;  // 0..8191
  const float4* p = (const float4*)(pstats + (size_t)r * 128);
  float mm = NEGBIG;
#pragma unroll
  for (int i = 0; i < 32; ++i) {
    float4 v = p[i];
    mm = fmaxf(mm, fmaxf(v.x, v.z));
  }
  float ll = 0.f;
#pragma unroll
  for (int i = 0; i < 32; ++i) {
    float4 v = p[i];
    ll += v.y * __expf(v.x - mm) + v.w * __expf(v.z - mm);
  }
  sm[r] = mm;
  slinv[r] = (ll > 0.f) ? (1.f / ll) : 0.f;
}

// ---------------- K4: p = exp(x-m)/l (once per element, in place) ; partial c = P@V ----
// grid (4 s-chunks, 16 t-tiles, 8 b) = 512 blocks, block 512 (8 waves: 2 t x 4 d)
// block tile 64t x 256d, src-chunk 1024 in 16 steps of 64. fp16 split-K partials.
__global__ __launch_bounds__(512, 4) void k_pv(const float* __restrict__ mbank,
                                               const float* __restrict__ sm,
                                               const float* __restrict__ slinv,
                                               float* __restrict__ alignv,
                                               f16* __restrict__ pc) {
  __shared__ __align__(16) f16 VT[256 * 64];  // [d][s] transposed, swizzled (32 KB)
  __shared__ __align__(16) f16 Ps[64 * 64];   // [t][s] p-tile fp16, swizzled (8 KB)
  const int tid = threadIdx.x;
  const int w = tid >> 6, l = tid & 63;
  const int wtg = w >> 2, wd = w & 3;  // wtg in {0,1} (32 rows), wd in {0..3} (64 d)
  const int q = l >> 4, lc = l & 15;
  const int kc = blockIdx.x;
  const int t0 = blockIdx.y * 64;
  const int b = blockIdx.z;
  const int s0 = kc * 1024;

  // p-conversion ownership: thread -> row pt (0..63), 8-wide s-slab ps8
  const int pt = tid >> 3;
  const int ps8 = (tid & 7) * 8;
  const float mv = sm[(size_t)b * NT + t0 + pt];
  const float lv = slinv[(size_t)b * NT + t0 + pt];
  float* xrow = alignv + ((size_t)b * NT + t0 + pt) * NS + s0 + ps8;

  f32x4 acc[2][4];
#pragma unroll
  for (int i = 0; i < 2; ++i)
#pragma unroll
    for (int j = 0; j < 4; ++j) acc[i][j] = (f32x4){0.f, 0.f, 0.f, 0.f};

  const int dstage = wd * 64 + l;   // this thread's V^T row (waves 0-3 / 4-7 alias)
  const int shalf = wtg * 32;       // which 32-s half this wave stages

  // prefetch x for step 0
  float4 xA = ((const float4*)xrow)[0];
  float4 xB = ((const float4*)xrow)[1];

  for (int st = 0; st < 16; ++st) {
    const int sb = s0 + st * 64;
    __syncthreads();  // prev step's MFMA done reading VT/Ps
    {  // stage V^T: 4 consecutive s at fixed d -> packed b64 write (32 elem/thread)
#pragma unroll
      for (int i = 0; i < 8; ++i) {
        const int s4 = shalf + i * 4;
        const float* g = mbank + ((size_t)b * NS + sb + s4) * ND + dstage;
        const float f0 = g[0], f1 = g[ND], f2 = g[2 * ND], f3 = g[3 * ND];
        half4v h = {(f16)f0, (f16)f1, (f16)f2, (f16)f3};
        *(half4v*)((char*)VT + dstage * 128 + swz(dstage, s4 * 2)) = h;
      }
    }
    {  // x -> p from prefetched regs; write p to global + fp16 to LDS
      const float p0 = __expf(xA.x - mv) * lv, p1 = __expf(xA.y - mv) * lv;
      const float p2 = __expf(xA.z - mv) * lv, p3 = __expf(xA.w - mv) * lv;
      const float p4 = __expf(xB.x - mv) * lv, p5 = __expf(xB.y - mv) * lv;
      const float p6 = __expf(xB.z - mv) * lv, p7 = __expf(xB.w - mv) * lv;
      float* xp = xrow + st * 64;
      ((float4*)xp)[0] = (float4){p0, p1, p2, p3};
      ((float4*)xp)[1] = (float4){p4, p5, p6, p7};
      half8 h = {(f16)p0, (f16)p1, (f16)p2, (f16)p3,
                 (f16)p4, (f16)p5, (f16)p6, (f16)p7};
      *(half8*)((char*)Ps + pt * 128 + swz(pt, ps8 * 2)) = h;
    }
    if (st < 15) {  // T14: issue next step's x loads (consumed next iteration)
      const float* xn = xrow + (st + 1) * 64;
      xA = ((const float4*)xn)[0];
      xB = ((const float4*)xn)[1];
    }
    __syncthreads();  // VT/Ps ready
    half8 a[2][2];
#pragma unroll
    for (int mb = 0; mb < 2; ++mb)
#pragma unroll
      for (int kf = 0; kf < 2; ++kf) {
        const int r = wtg * 32 + mb * 16 + lc;
        a[mb][kf] = *(const half8*)((const char*)Ps + r * 128 + swz(r, kf * 64 + q * 16));
      }
#pragma unroll
    for (int kf = 0; kf < 2; ++kf)
#pragma unroll
      for (int nb = 0; nb < 4; ++nb) {
        const int d = wd * 64 + nb * 16 + lc;
        half8 bbt = *(const half8*)((const char*)VT + d * 128 + swz(d, kf * 64 + q * 16));
#pragma unroll
        for (int mb = 0; mb < 2; ++mb)
          acc[mb][nb] = MFMA16(a[mb][kf], bbt, acc[mb][nb]);
      }
  }

#pragma unroll
  for (int mb = 0; mb < 2; ++mb)
#pragma unroll
    for (int nb = 0; nb < 4; ++nb)
#pragma unroll
      for (int j = 0; j < 4; ++j) {
        const int t = t0 + wtg * 32 + mb * 16 + q * 4 + j;
        const int d = wd * 64 + nb * 16 + lc;
        pc[(size_t)kc * ((size_t)NBATCH * NT * ND) + ((size_t)b * NT + t) * ND + d] =
            (f16)acc[mb][nb][j];
      }
}

// ---------------- K5: c = sum of 4 fp16 split-K partials ----------------
__global__ __launch_bounds__(256) void k_csum(const f16* __restrict__ pc,
                                              float* __restrict__ outc) {
  const size_t i8 = ((size_t)blockIdx.x * 256 + threadIdx.x) * 8;
  const size_t STRIDE = (size_t)NBATCH * NT * ND;  // 2097152
  half8 a = *(const half8*)(pc + i8);
  half8 b = *(const half8*)(pc + STRIDE + i8);
  half8 c = *(const half8*)(pc + 2 * STRIDE + i8);
  half8 d = *(const half8*)(pc + 3 * STRIDE + i8);
  float4 r0, r1;
  r0.x = (float)a[0] + (float)b[0] + (float)c[0] + (float)d[0];
  r0.y = (float)a[1] + (float)b[1] + (float)c[1] + (float)d[1];
  r0.z = (float)a[2] + (float)b[2] + (float)c[2] + (float)d[2];
  r0.w = (float)a[3] + (float)b[3] + (float)c[3] + (float)d[3];
  r1.x = (float)a[4] + (float)b[4] + (float)c[4] + (float)d[4];
  r1.y = (float)a[5] + (float)b[5] + (float)c[5] + (float)d[5];
  r1.z = (float)a[6] + (float)b[6] + (float)c[6] + (float)d[6];
  r1.w = (float)a[7] + (float)b[7] + (float)c[7] + (float)d[7];
  *(float4*)(outc + i8) = r0;
  *(float4*)(outc + i8 + 4) = r1;
}

extern "C" void kernel_launch(void* const* d_in, const int* in_sizes, int n_in,
                              void* d_out, int out_size, void* d_ws, size_t ws_size,
                              hipStream_t stream) {
  const float* mbank = (const float*)d_in[0];  // (8,4096,256) f32
  const float* src   = (const float*)d_in[1];  // (8,1024,256) f32
  const int*   mask  = (const int*)d_in[2];    // (8,4096) bool->int
  const float* W     = (const float*)d_in[3];  // (256,256) f32

  float* out_c = (float*)d_out;                         // 2,097,152 f32
  float* out_align = out_c + (size_t)NBATCH * NT * ND;  // 33,554,432 f32

  // ws layout (pc overlays q16+pstats, which are dead by the time K4 writes pc):
  //   [0, 16777216)           pc   : 4 x 2M fp16 split-K partials    (K4 -> K5)
  //   [0, 4194304)            q16  : 8192x256 fp16                    (K1 -> K2)
  //   [4194304, 8388608)      pstats: 8192x64x2 f32                   (K2 -> K3)
  //   [33554432, 33587200)    sm   : 8192 f32
  //   [33587200, 33619968)    slinv: 8192 f32
  char* ws = (char*)d_ws;
  f16* q16      = (f16*)ws;
  float* pstats = (float*)(ws + 4194304);
  f16* pc       = (f16*)ws;
  float* sm     = (float*)(ws + 33554432);
  float* slinv  = (float*)(ws + 33587200);

  hipLaunchKernelGGL(k_qproj, dim3(128), dim3(256), 0, stream, src, W, q16);
  hipLaunchKernelGGL(k_logits, dim3(64, 8, 8), dim3(256), 0, stream,
                     mbank, q16, mask, out_align, pstats);
  hipLaunchKernelGGL(k_stats, dim3(32), dim3(256), 0, stream, pstats, sm, slinv);
  hipLaunchKernelGGL(k_pv, dim3(4, 16, 8), dim3(512), 0, stream,
                     mbank, sm, slinv, out_align, pc);
  hipLaunchKernelGGL(k_csum, dim3(1024), dim3(256), 0, stream, pc, out_c);
}